// Round 17
// baseline (95.128 us; speedup 1.0000x reference)
//
#include <hip/hip_runtime.h>
#include <hip/hip_fp16.h>

typedef _Float16 half8  __attribute__((ext_vector_type(8)));
typedef _Float16 half4v __attribute__((ext_vector_type(4)));
typedef float    f32x4  __attribute__((ext_vector_type(4)));

#define MFMA_F16 __builtin_amdgcn_mfma_f32_16x16x32_f16

// raw barrier: fence LDS (lgkmcnt) but do NOT drain in-flight global loads (vmcnt)
#define BAR_LDS() asm volatile("s_waitcnt lgkmcnt(0)\n\ts_barrier" ::: "memory")
// barrier for global_load_lds staging: drain vmcnt (loads issued a full phase ago)
#define BAR_VM()  asm volatile("s_waitcnt vmcnt(0)\n\ts_barrier" ::: "memory")

__device__ __forceinline__ unsigned pack_f16(float a, float b) {
    union { __fp16 h __attribute__((ext_vector_type(2))); unsigned u; } cv;
    cv.h = __builtin_amdgcn_cvt_pkrtz(a, b);
    return cv.u;
}

__device__ __forceinline__ void gload16(const _Float16* g, _Float16* l) {
    __builtin_amdgcn_global_load_lds((const __attribute__((address_space(1))) void*)g,
                                     (__attribute__((address_space(3))) void*)l, 16, 0, 0);
}

// ---------------- kernel 0: W_q|W_k|W_v f32 -> concat f16 [384][1024] ----------------
__global__ __launch_bounds__(256) void wconv_k(const float* __restrict__ wq,
                                               const float* __restrict__ wk,
                                               const float* __restrict__ wv,
                                               _Float16* __restrict__ wh) {
    int i = (blockIdx.x * 256 + threadIdx.x) * 8;
    const float* src; int off;
    if (i < 131072)      { src = wq; off = i; }
    else if (i < 262144) { src = wk; off = i - 131072; }
    else                 { src = wv; off = i - 262144; }
    float4 a = *(const float4*)(src + off);
    float4 b = *(const float4*)(src + off + 4);
    half8 h;
    h[0]=(_Float16)a.x; h[1]=(_Float16)a.y; h[2]=(_Float16)a.z; h[3]=(_Float16)a.w;
    h[4]=(_Float16)b.x; h[5]=(_Float16)b.y; h[6]=(_Float16)b.z; h[7]=(_Float16)b.w;
    *(half8*)(wh + i) = h;
}

// ---------------- kernel 1: fused QKV projection (unchanged from R16) ----------------
__global__ __launch_bounds__(256, 3) void qkv_k(const float* __restrict__ x,
                                                const _Float16* __restrict__ wh,
                                                _Float16* __restrict__ qh,
                                                _Float16* __restrict__ kh,
                                                _Float16* __restrict__ vth) {
    __shared__ _Float16 xs[2][64 * 136];
    const int tid = threadIdx.x;
    const int w = tid >> 6, l = tid & 63;
    const int fr = l & 15, fq = l >> 4;
    const int bid = blockIdx.x;
    const int xcd = bid & 7;
    const int slot = bid >> 3;
    const int rb = (slot / 3) * 8 + xcd;
    const int cb = slot % 3;
    const int row0 = rb * 64;
    const int c0 = cb * 128 + w * 32;

    const int srow = tid >> 2, sg = tid & 3;
    const float* xg = x + (row0 + srow) * 1024 + sg * 4;
    const _Float16* wgb = wh + (c0 + fr) * 1024 + fq * 8;

    f32x4 acc[4][2] = {};
    float4 xa[8];
    half8 wf[4][2];                        // W ring: slot ss&3 holds substep ss

    // prologue: W slots 0..2, then tile0 -> LDS, tile1 -> regs
#pragma unroll
    for (int ss = 0; ss < 3; ++ss)
#pragma unroll
        for (int nf = 0; nf < 2; ++nf)
            wf[ss][nf] = *(const half8*)(wgb + nf * 16384 + ss * 32);
#pragma unroll
    for (int i = 0; i < 8; ++i) xa[i] = *(const float4*)(xg + i * 16);
#pragma unroll
    for (int i = 0; i < 8; ++i) {
        float4 t = xa[i]; half4v hv;
        hv[0]=(_Float16)t.x; hv[1]=(_Float16)t.y; hv[2]=(_Float16)t.z; hv[3]=(_Float16)t.w;
        *(half4v*)(&xs[0][srow * 136 + sg * 4 + i * 16]) = hv;
    }
#pragma unroll
    for (int i = 0; i < 8; ++i) xa[i] = *(const float4*)(xg + 128 + i * 16);
    BAR_LDS();

    int cur = 0;
    for (int kt = 0; kt < 8; ++kt) {
#pragma unroll
        for (int s = 0; s < 4; ++s) {
            const int ss = kt * 4 + s;
            if (ss + 3 < 32) {             // issue W for substep ss+3 (ring distance 3)
#pragma unroll
                for (int nf = 0; nf < 2; ++nf)
                    wf[(ss + 3) & 3][nf] = *(const half8*)(wgb + nf * 16384 + (ss + 3) * 32);
            }
            half8 af[4];
#pragma unroll
            for (int mf = 0; mf < 4; ++mf)
                af[mf] = *(const half8*)(&xs[cur][(mf * 16 + fr) * 136 + s * 32 + fq * 8]);
#pragma unroll
            for (int mf = 0; mf < 4; ++mf)
#pragma unroll
                for (int nf = 0; nf < 2; ++nf)
                    acc[mf][nf] = MFMA_F16(af[mf], wf[ss & 3][nf], acc[mf][nf], 0, 0, 0);
        }
        if (kt < 7) {
#pragma unroll
            for (int i = 0; i < 8; ++i) {
                float4 t = xa[i]; half4v hv;
                hv[0]=(_Float16)t.x; hv[1]=(_Float16)t.y; hv[2]=(_Float16)t.z; hv[3]=(_Float16)t.w;
                *(half4v*)(&xs[cur ^ 1][srow * 136 + sg * 4 + i * 16]) = hv;
            }
            if (kt < 6) {
#pragma unroll
                for (int i = 0; i < 8; ++i)
                    xa[i] = *(const float4*)(xg + (kt + 2) * 128 + i * 16);
            }
        }
        BAR_LDS();
        cur ^= 1;
    }

    // epilogue: block-uniform destination (cb 0->Q, 1->K, 2->V-permuted)
#pragma unroll
    for (int nf = 0; nf < 2; ++nf) {
        int n0 = c0 + nf * 16 + fr;
#pragma unroll
        for (int mf = 0; mf < 4; ++mf) {
            int mb = row0 + mf * 16 + fq * 4;
            if (cb == 0) {
#pragma unroll
                for (int r = 0; r < 4; ++r) qh[(mb + r) * 128 + n0] = (_Float16)acc[mf][nf][r];
            } else if (cb == 1) {
#pragma unroll
                for (int r = 0; r < 4; ++r) kh[(mb + r) * 128 + (n0 - 128)] = (_Float16)acc[mf][nf][r];
            } else {
                half4v pv;
#pragma unroll
                for (int r = 0; r < 4; ++r) pv[r] = (_Float16)acc[mf][nf][r];
                int t = mb & 2047;
                int tl = t & 63;
                int tp = (t & ~63) | (tl & 35) | ((tl & 12) << 1) | ((tl & 16) >> 2);
                *(half4v*)(&vth[((mb >> 11) * 128 + (n0 - 256)) * 2048 + tp]) = pv;
            }
        }
    }
}

// ---------------- kernel 2: causal flash attention, global_load_lds staging ----------------
// 576 blocks x 512 threads (8 waves). Staging via global_load_lds width=16: LDS dest linear
// (wave base + lane*16), XOR swizzle applied to the per-lane GLOBAL source (rule #21).
// Tile j+2 issued after the barrier -> full compute phase of latency cover.
__global__ __launch_bounds__(512, 4) void attn_k(const _Float16* __restrict__ qh,
                                                 const _Float16* __restrict__ kh,
                                                 const _Float16* __restrict__ vth,
                                                 _Float16* __restrict__ part,
                                                 float* __restrict__ stats,
                                                 float* __restrict__ out) {
    __shared__ _Float16 ks[2][32 * 128];   // K tiles (swizzled layout via source perm)
    __shared__ _Float16 vs[2][128 * 32];   // Vt tiles (slot order), swizzled via source perm

    int bid = blockIdx.x;
    int b = bid & 7;
    int u = bid >> 3;
    int qt, c;
    {
        int idx = u;
        qt = 0;
        for (;;) { int nc = (qt >> 1) + 1; if (idx < nc) break; idx -= nc; ++qt; }
        c = idx;
    }
    int j0 = c * 8;
    int jmax = 4 * qt + 4;
    int j1 = j0 + 8 < jmax ? j0 + 8 : jmax;

    int tid = threadIdx.x, w = tid >> 6, l = tid & 63;
    int fr = l & 15, fq = l >> 4;
    int xw = (fr & 7) << 4;                    // K-row XOR key (read side)
    int xv = (fr & 3) << 4;                    // V-row XOR key (read side)

    // pre-swizzled global source lanes for gload staging
    const int kr  = tid >> 4;                  // K row 0..31
    const int kc  = (tid & 15) ^ (kr & 7);     // pre-swizzled 16B column
    const int vdd = tid >> 2;                  // V d-row 0..127
    const int vc  = (tid & 3) ^ (vdd & 3);     // pre-swizzled 16B column

    half8 qf[4];
    const _Float16* qp = qh + ((b * 2048 + qt * 128 + w * 16 + fr) << 7);
#pragma unroll
    for (int cc = 0; cc < 4; ++cc) qf[cc] = *(const half8*)(qp + cc * 32 + fq * 8);

#define GLOAD_TILE(j, bb) do {                                                            \
    gload16(kh + (((b << 11) + ((j) << 5) + kr) << 7) + kc * 8, &ks[bb][0] + w * 512);    \
    gload16(vth + (((b << 7) + vdd) << 11) + ((j) << 5) + vc * 8, &vs[bb][0] + w * 512);  \
    } while (0)

    f32x4 acc[8] = {};                 // O^T: lane q = qt*128 + w*16 + fr; d = dt*16 + fq*4 + r
    float mrow = -1e30f, lrow = 0.0f;  // per-lane (q) scalars

    GLOAD_TILE(j0, 0);
    BAR_VM();                          // tile j0 ready
    if (j0 + 1 < j1) GLOAD_TILE(j0 + 1, 1);   // overlaps iter j0 compute

    int cur = 0;
    for (int j = j0; j < j1; ++j) {
        const char* ksb = (const char*)(ks[cur]);
        const char* vsb = (const char*)(vs[cur]);

        // ---- S^T = K Q^T: lane q = fr; kv = n*16 + fq*4 + r ----
        f32x4 s[2] = {};
        __builtin_amdgcn_s_setprio(1);
#pragma unroll
        for (int n = 0; n < 2; ++n) {
            const char* krow = ksb + (n * 16 + fr) * 256;
#pragma unroll
            for (int cc = 0; cc < 4; ++cc) {
                half8 kf = *(const half8*)(krow + ((cc * 64 + fq * 16) ^ xw));
                s[n] = MFMA_F16(kf, qf[cc], s[n], 0, 0, 0);
            }
        }
        __builtin_amdgcn_s_setprio(0);
        const float sc = 0.088388347648318447f;  // 1/sqrt(128)
        if (j >= 4 * qt) {
            int koff = (j - 4 * qt) << 5;
            int qrow = w * 16 + fr;
#pragma unroll
            for (int n = 0; n < 2; ++n)
#pragma unroll
                for (int r = 0; r < 4; ++r) {
                    int kcol = koff + n * 16 + fq * 4 + r;
                    float v = s[n][r] * sc;
                    s[n][r] = (kcol > qrow) ? -1e30f : v;
                }
        } else {
#pragma unroll
            for (int n = 0; n < 2; ++n)
#pragma unroll
                for (int r = 0; r < 4; ++r) s[n][r] *= sc;
        }

        // ---- online softmax: per-lane row stats, 2 shfl total ----
        float mx = s[0][0];
#pragma unroll
        for (int n = 0; n < 2; ++n)
#pragma unroll
            for (int r = 0; r < 4; ++r) mx = fmaxf(mx, s[n][r]);
        mx = fmaxf(mx, __shfl_xor(mx, 16));
        mx = fmaxf(mx, __shfl_xor(mx, 32));
        float nm = fmaxf(mrow, mx);
        float al = __expf(mrow - nm);
        mrow = nm;
        float rs = 0.f;
#pragma unroll
        for (int n = 0; n < 2; ++n)
#pragma unroll
            for (int r = 0; r < 4; ++r) {
                float p = __expf(s[n][r] - mrow);
                s[n][r] = p;
                rs += p;
            }
        rs += __shfl_xor(rs, 16);
        rs += __shfl_xor(rs, 32);
        lrow = lrow * al + rs;
#pragma unroll
        for (int dt = 0; dt < 8; ++dt)
#pragma unroll
            for (int r = 0; r < 4; ++r) acc[dt][r] *= al;

        // ---- P -> f16 in-register; B-frag = lane's OWN values (slot-permuted kv) ----
        union { unsigned u[4]; half8 h; } pb;
        pb.u[0] = pack_f16(s[0][0], s[0][1]);
        pb.u[1] = pack_f16(s[0][2], s[0][3]);
        pb.u[2] = pack_f16(s[1][0], s[1][1]);
        pb.u[3] = pack_f16(s[1][2], s[1][3]);

        __builtin_amdgcn_s_setprio(1);
#pragma unroll
        for (int dt = 0; dt < 8; ++dt) {
            const char* vrow = vsb + (dt * 16 + fr) * 64;
            half8 vf = *(const half8*)(vrow + ((fq * 16) ^ xv));
            acc[dt] = MFMA_F16(vf, pb.h, acc[dt], 0, 0, 0);
        }
        __builtin_amdgcn_s_setprio(0);

        BAR_VM();                        // tile j+1 landed (issued a full phase ago)
        if (j + 2 < j1) GLOAD_TILE(j + 2, cur);   // cur's readers all passed the barrier
        cur ^= 1;
    }

    float inv = 1.0f / lrow;

    if (qt < 2) {
        // single chunk: O^T -> out directly
        float* op = out + ((b * 2048 + qt * 128 + w * 16 + fr) << 7) + fq * 4;
#pragma unroll
        for (int dt = 0; dt < 8; ++dt) {
            float4 o;
            o.x = acc[dt][0] * inv; o.y = acc[dt][1] * inv;
            o.z = acc[dt][2] * inv; o.w = acc[dt][3] * inv;
            *(float4*)(op + dt * 16) = o;
        }
    } else {
        // partial: part[bid][w][dt][l][r]  (per-wave 4 KB region)
        _Float16* op = part + bid * 16384 + w * 2048 + l * 4;
#pragma unroll
        for (int dt = 0; dt < 8; ++dt) {
            half4v h;
#pragma unroll
            for (int r = 0; r < 4; ++r) h[r] = (_Float16)(acc[dt][r] * inv);
            *(half4v*)(op + dt * 256) = h;
        }
        if (l < 16) {
            int ridx = bid * 128 + w * 16 + l;
            float2 st; st.x = mrow; st.y = lrow;
            *(float2*)(&stats[ridx * 2]) = st;
        }
    }
#undef GLOAD_TILE
}

// ---------------- kernel 3: combine split-KV partials (qt >= 2, nc in [2,8]) ----------------
__global__ __launch_bounds__(256) void comb_k(const _Float16* __restrict__ part,
                                              const float* __restrict__ stats,
                                              float* __restrict__ out) {
    int bid = blockIdx.x;
    int b = bid & 7, qt = 2 + (bid >> 3);
    int h = qt >> 1;
    int nc = h + 1;
    int u0 = qt + h * (h - 1) + (qt & 1) * h;
    int t = threadIdx.x;
    int row = t >> 1, g = t & 1;
    int w = row >> 4, q16 = row & 15;

    float mstar = -1e30f, mv[8], lv[8];
#pragma unroll
    for (int cc = 0; cc < 8; ++cc) {
        if (cc < nc) {
            int sidx = (((u0 + cc) << 3) + b) * 128 + row;
            mv[cc] = stats[sidx * 2];
            lv[cc] = stats[sidx * 2 + 1];
            mstar = fmaxf(mstar, mv[cc]);
        }
    }
    float den = 0.f, wc[8];
#pragma unroll
    for (int cc = 0; cc < 8; ++cc) {
        if (cc < nc) { wc[cc] = __expf(mv[cc] - mstar) * lv[cc]; den += wc[cc]; }
        else wc[cc] = 0.f;
    }
    // a[dd*16 + fq*4 + r] for dt = 4g + dd
    float a[64] = {};
#pragma unroll
    for (int cc = 0; cc < 8; ++cc) {
        if (cc < nc) {
            const _Float16* pp = part + ((((u0 + cc) << 3) + b) * 16384) + w * 2048;
            float wcc = wc[cc];
#pragma unroll
            for (int dd = 0; dd < 4; ++dd) {
                int dt = 4 * g + dd;
#pragma unroll
                for (int fq = 0; fq < 4; ++fq) {
                    half4v hh = *(const half4v*)(pp + dt * 256 + (fq * 16 + q16) * 4);
#pragma unroll
                    for (int r = 0; r < 4; ++r)
                        a[dd * 16 + fq * 4 + r] += wcc * (float)hh[r];
                }
            }
        }
    }
    float id = 1.0f / den;
    float* op = out + (b * 2048 + qt * 128 + row) * 128 + g * 64;
#pragma unroll
    for (int uu = 0; uu < 16; ++uu) {
        float4 o;
        o.x = a[uu * 4]     * id;
        o.y = a[uu * 4 + 1] * id;
        o.z = a[uu * 4 + 2] * id;
        o.w = a[uu * 4 + 3] * id;
        *(float4*)(op + uu * 4) = o;
    }
}

extern "C" void kernel_launch(void* const* d_in, const int* in_sizes, int n_in,
                              void* d_out, int out_size, void* d_ws, size_t ws_size,
                              hipStream_t stream) {
    const float* x  = (const float*)d_in[0];
    const float* wq = (const float*)d_in[1];
    const float* wk = (const float*)d_in[2];
    const float* wv = (const float*)d_in[3];

    char* ws = (char*)d_ws;
    _Float16* wh   = (_Float16*)(ws);                    // 768 KB
    _Float16* qhp  = (_Float16*)(ws + (1u  << 20));      // 4 MB
    _Float16* khp  = (_Float16*)(ws + (5u  << 20));      // 4 MB
    _Float16* vtp  = (_Float16*)(ws + (9u  << 20));      // 4 MB
    _Float16* part = (_Float16*)(ws + (13u << 20));      // 576*32KB = 18 MB
    float*    stat = (float*)   (ws + (32u << 20));      // 590 KB

    wconv_k<<<192, 256, 0, stream>>>(wq, wk, wv, wh);
    qkv_k<<<768, 256, 0, stream>>>(x, wh, qhp, khp, vtp);
    attn_k<<<576, 512, 0, stream>>>(qhp, khp, vtp, part, stat, (float*)d_out);
    comb_k<<<112, 256, 0, stream>>>(part, stat, (float*)d_out);
}

// Round 18
// 93.787 us; speedup vs baseline: 1.0143x; 1.0143x over previous
//
#include <hip/hip_runtime.h>
#include <hip/hip_fp16.h>

typedef _Float16 half8  __attribute__((ext_vector_type(8)));
typedef _Float16 half4v __attribute__((ext_vector_type(4)));
typedef float    f32x4  __attribute__((ext_vector_type(4)));

#define MFMA_F16 __builtin_amdgcn_mfma_f32_16x16x32_f16

// raw barrier: fence LDS (lgkmcnt) but do NOT drain in-flight global loads (vmcnt)
#define BAR_LDS() asm volatile("s_waitcnt lgkmcnt(0)\n\ts_barrier" ::: "memory")
// barrier for global_load_lds staging: drain vmcnt (loads issued a full phase ago)
#define BAR_VM()  asm volatile("s_waitcnt vmcnt(0)\n\ts_barrier" ::: "memory")

__device__ __forceinline__ unsigned pack_f16(float a, float b) {
    union { __fp16 h __attribute__((ext_vector_type(2))); unsigned u; } cv;
    cv.h = __builtin_amdgcn_cvt_pkrtz(a, b);
    return cv.u;
}

__device__ __forceinline__ void gload16(const _Float16* g, _Float16* l) {
    __builtin_amdgcn_global_load_lds((const __attribute__((address_space(1))) void*)g,
                                     (__attribute__((address_space(3))) void*)l, 16, 0, 0);
}

// ---------------- kernel 0: W_q|W_k|W_v f32 -> concat f16 [384][1024] ----------------
__global__ __launch_bounds__(256) void wconv_k(const float* __restrict__ wq,
                                               const float* __restrict__ wk,
                                               const float* __restrict__ wv,
                                               _Float16* __restrict__ wh) {
    int i = (blockIdx.x * 256 + threadIdx.x) * 8;
    const float* src; int off;
    if (i < 131072)      { src = wq; off = i; }
    else if (i < 262144) { src = wk; off = i - 131072; }
    else                 { src = wv; off = i - 262144; }
    float4 a = *(const float4*)(src + off);
    float4 b = *(const float4*)(src + off + 4);
    half8 h;
    h[0]=(_Float16)a.x; h[1]=(_Float16)a.y; h[2]=(_Float16)a.z; h[3]=(_Float16)a.w;
    h[4]=(_Float16)b.x; h[5]=(_Float16)b.y; h[6]=(_Float16)b.z; h[7]=(_Float16)b.w;
    *(half8*)(wh + i) = h;
}

// ---------------- kernel 1: fused QKV projection ----------------
// grid 768, XCD-pinned. NEW: af register double-buffer (afA/afB) — next substep's
// ds_reads issued before this substep's MFMAs, hiding LDS latency in-wave.
__global__ __launch_bounds__(256, 3) void qkv_k(const float* __restrict__ x,
                                                const _Float16* __restrict__ wh,
                                                _Float16* __restrict__ qh,
                                                _Float16* __restrict__ kh,
                                                _Float16* __restrict__ vth) {
    __shared__ _Float16 xs[2][64 * 136];
    const int tid = threadIdx.x;
    const int w = tid >> 6, l = tid & 63;
    const int fr = l & 15, fq = l >> 4;
    const int bid = blockIdx.x;
    const int xcd = bid & 7;
    const int slot = bid >> 3;
    const int rb = (slot / 3) * 8 + xcd;
    const int cb = slot % 3;
    const int row0 = rb * 64;
    const int c0 = cb * 128 + w * 32;

    const int srow = tid >> 2, sg = tid & 3;
    const float* xg = x + (row0 + srow) * 1024 + sg * 4;
    const _Float16* wgb = wh + (c0 + fr) * 1024 + fq * 8;

    f32x4 acc[4][2] = {};
    float4 xa[8];
    half8 wf[4][2];                        // W ring: slot ss&3 holds substep ss

    // prologue: W slots 0..2, then tile0 -> LDS, tile1 -> regs
#pragma unroll
    for (int ss = 0; ss < 3; ++ss)
#pragma unroll
        for (int nf = 0; nf < 2; ++nf)
            wf[ss][nf] = *(const half8*)(wgb + nf * 16384 + ss * 32);
#pragma unroll
    for (int i = 0; i < 8; ++i) xa[i] = *(const float4*)(xg + i * 16);
#pragma unroll
    for (int i = 0; i < 8; ++i) {
        float4 t = xa[i]; half4v hv;
        hv[0]=(_Float16)t.x; hv[1]=(_Float16)t.y; hv[2]=(_Float16)t.z; hv[3]=(_Float16)t.w;
        *(half4v*)(&xs[0][srow * 136 + sg * 4 + i * 16]) = hv;
    }
#pragma unroll
    for (int i = 0; i < 8; ++i) xa[i] = *(const float4*)(xg + 128 + i * 16);
    BAR_LDS();

#define SUBSTEP(s, AFC, AFN)                                                              \
    {                                                                                     \
        const int ss = kt * 4 + s;                                                        \
        if (ss + 3 < 32) {                                                                \
            _Pragma("unroll")                                                             \
            for (int nf = 0; nf < 2; ++nf)                                                \
                wf[(ss + 3) & 3][nf] = *(const half8*)(wgb + nf * 16384 + (ss + 3) * 32); \
        }                                                                                 \
        if (s < 3) {                                                                      \
            _Pragma("unroll")                                                             \
            for (int mf = 0; mf < 4; ++mf)                                                \
                AFN[mf] = *(const half8*)(&xs[cur][(mf * 16 + fr) * 136 + (s + 1) * 32 + fq * 8]); \
        }                                                                                 \
        _Pragma("unroll")                                                                 \
        for (int mf = 0; mf < 4; ++mf)                                                    \
            _Pragma("unroll")                                                             \
            for (int nf = 0; nf < 2; ++nf)                                                \
                acc[mf][nf] = MFMA_F16(AFC[mf], wf[ss & 3][nf], acc[mf][nf], 0, 0, 0);    \
    }

    int cur = 0;
    for (int kt = 0; kt < 8; ++kt) {
        half8 afA[4], afB[4];
#pragma unroll
        for (int mf = 0; mf < 4; ++mf)
            afA[mf] = *(const half8*)(&xs[cur][(mf * 16 + fr) * 136 + fq * 8]);
        SUBSTEP(0, afA, afB)
        SUBSTEP(1, afB, afA)
        SUBSTEP(2, afA, afB)
        SUBSTEP(3, afB, afA)
        if (kt < 7) {
#pragma unroll
            for (int i = 0; i < 8; ++i) {
                float4 t = xa[i]; half4v hv;
                hv[0]=(_Float16)t.x; hv[1]=(_Float16)t.y; hv[2]=(_Float16)t.z; hv[3]=(_Float16)t.w;
                *(half4v*)(&xs[cur ^ 1][srow * 136 + sg * 4 + i * 16]) = hv;
            }
            if (kt < 6) {
#pragma unroll
                for (int i = 0; i < 8; ++i)
                    xa[i] = *(const float4*)(xg + (kt + 2) * 128 + i * 16);
            }
        }
        BAR_LDS();
        cur ^= 1;
    }
#undef SUBSTEP

    // epilogue: block-uniform destination (cb 0->Q, 1->K, 2->V-permuted)
#pragma unroll
    for (int nf = 0; nf < 2; ++nf) {
        int n0 = c0 + nf * 16 + fr;
#pragma unroll
        for (int mf = 0; mf < 4; ++mf) {
            int mb = row0 + mf * 16 + fq * 4;
            if (cb == 0) {
#pragma unroll
                for (int r = 0; r < 4; ++r) qh[(mb + r) * 128 + n0] = (_Float16)acc[mf][nf][r];
            } else if (cb == 1) {
#pragma unroll
                for (int r = 0; r < 4; ++r) kh[(mb + r) * 128 + (n0 - 128)] = (_Float16)acc[mf][nf][r];
            } else {
                half4v pv;
#pragma unroll
                for (int r = 0; r < 4; ++r) pv[r] = (_Float16)acc[mf][nf][r];
                int t = mb & 2047;
                int tl = t & 63;
                int tp = (t & ~63) | (tl & 35) | ((tl & 12) << 1) | ((tl & 16) >> 2);
                *(half4v*)(&vth[((mb >> 11) * 128 + (n0 - 256)) * 2048 + tp]) = pv;
            }
        }
    }
}

// ---------------- kernel 2: causal flash attention + defer-max (T13) ----------------
__global__ __launch_bounds__(512, 4) void attn_k(const _Float16* __restrict__ qh,
                                                 const _Float16* __restrict__ kh,
                                                 const _Float16* __restrict__ vth,
                                                 _Float16* __restrict__ part,
                                                 float* __restrict__ stats,
                                                 float* __restrict__ out) {
    __shared__ _Float16 ks[2][32 * 128];
    __shared__ _Float16 vs[2][128 * 32];

    int bid = blockIdx.x;
    int b = bid & 7;
    int u = bid >> 3;
    int qt, c;
    {
        int idx = u;
        qt = 0;
        for (;;) { int nc = (qt >> 1) + 1; if (idx < nc) break; idx -= nc; ++qt; }
        c = idx;
    }
    int j0 = c * 8;
    int jmax = 4 * qt + 4;
    int j1 = j0 + 8 < jmax ? j0 + 8 : jmax;

    int tid = threadIdx.x, w = tid >> 6, l = tid & 63;
    int fr = l & 15, fq = l >> 4;
    int xw = (fr & 7) << 4;
    int xv = (fr & 3) << 4;

    const int kr  = tid >> 4;
    const int kc  = (tid & 15) ^ (kr & 7);
    const int vdd = tid >> 2;
    const int vc  = (tid & 3) ^ (vdd & 3);

    half8 qf[4];
    const _Float16* qp = qh + ((b * 2048 + qt * 128 + w * 16 + fr) << 7);
#pragma unroll
    for (int cc = 0; cc < 4; ++cc) qf[cc] = *(const half8*)(qp + cc * 32 + fq * 8);

#define GLOAD_TILE(j, bb) do {                                                            \
    gload16(kh + (((b << 11) + ((j) << 5) + kr) << 7) + kc * 8, &ks[bb][0] + w * 512);    \
    gload16(vth + (((b << 7) + vdd) << 11) + ((j) << 5) + vc * 8, &vs[bb][0] + w * 512);  \
    } while (0)

    f32x4 acc[8] = {};
    float mrow = -1e30f, lrow = 0.0f;

    GLOAD_TILE(j0, 0);
    BAR_VM();
    if (j0 + 1 < j1) GLOAD_TILE(j0 + 1, 1);

    int cur = 0;
    for (int j = j0; j < j1; ++j) {
        const char* ksb = (const char*)(ks[cur]);
        const char* vsb = (const char*)(vs[cur]);

        // ---- S^T = K Q^T: lane q = fr; kv = n*16 + fq*4 + r ----
        f32x4 s[2] = {};
        __builtin_amdgcn_s_setprio(1);
#pragma unroll
        for (int n = 0; n < 2; ++n) {
            const char* krow = ksb + (n * 16 + fr) * 256;
#pragma unroll
            for (int cc = 0; cc < 4; ++cc) {
                half8 kf = *(const half8*)(krow + ((cc * 64 + fq * 16) ^ xw));
                s[n] = MFMA_F16(kf, qf[cc], s[n], 0, 0, 0);
            }
        }
        __builtin_amdgcn_s_setprio(0);
        const float sc = 0.088388347648318447f;  // 1/sqrt(128)
        if (j >= 4 * qt) {
            int koff = (j - 4 * qt) << 5;
            int qrow = w * 16 + fr;
#pragma unroll
            for (int n = 0; n < 2; ++n)
#pragma unroll
                for (int r = 0; r < 4; ++r) {
                    int kcol = koff + n * 16 + fq * 4 + r;
                    float v = s[n][r] * sc;
                    s[n][r] = (kcol > qrow) ? -1e30f : v;
                }
        } else {
#pragma unroll
            for (int n = 0; n < 2; ++n)
#pragma unroll
                for (int r = 0; r < 4; ++r) s[n][r] *= sc;
        }

        // ---- online softmax with defer-max (T13): skip shfl-max + rescale if bounded ----
        float pmax = s[0][0];
#pragma unroll
        for (int n = 0; n < 2; ++n)
#pragma unroll
            for (int r = 0; r < 4; ++r) pmax = fmaxf(pmax, s[n][r]);
        float al = 1.0f;
        if (!__all(pmax - mrow <= 8.0f)) {
            float mx = pmax;
            mx = fmaxf(mx, __shfl_xor(mx, 16));
            mx = fmaxf(mx, __shfl_xor(mx, 32));
            float nm = fmaxf(mrow, mx);
            al = __expf(mrow - nm);
            mrow = nm;
#pragma unroll
            for (int dt = 0; dt < 8; ++dt)
#pragma unroll
                for (int r = 0; r < 4; ++r) acc[dt][r] *= al;
        }
        float rs = 0.f;
#pragma unroll
        for (int n = 0; n < 2; ++n)
#pragma unroll
            for (int r = 0; r < 4; ++r) {
                float p = __expf(s[n][r] - mrow);
                s[n][r] = p;
                rs += p;
            }
        rs += __shfl_xor(rs, 16);
        rs += __shfl_xor(rs, 32);
        lrow = lrow * al + rs;

        // ---- P -> f16 in-register; B-frag = lane's OWN values (slot-permuted kv) ----
        union { unsigned u[4]; half8 h; } pb;
        pb.u[0] = pack_f16(s[0][0], s[0][1]);
        pb.u[1] = pack_f16(s[0][2], s[0][3]);
        pb.u[2] = pack_f16(s[1][0], s[1][1]);
        pb.u[3] = pack_f16(s[1][2], s[1][3]);

        __builtin_amdgcn_s_setprio(1);
#pragma unroll
        for (int dt = 0; dt < 8; ++dt) {
            const char* vrow = vsb + (dt * 16 + fr) * 64;
            half8 vf = *(const half8*)(vrow + ((fq * 16) ^ xv));
            acc[dt] = MFMA_F16(vf, pb.h, acc[dt], 0, 0, 0);
        }
        __builtin_amdgcn_s_setprio(0);

        BAR_VM();
        if (j + 2 < j1) GLOAD_TILE(j + 2, cur);
        cur ^= 1;
    }

    float inv = 1.0f / lrow;

    if (qt < 2) {
        float* op = out + ((b * 2048 + qt * 128 + w * 16 + fr) << 7) + fq * 4;
#pragma unroll
        for (int dt = 0; dt < 8; ++dt) {
            float4 o;
            o.x = acc[dt][0] * inv; o.y = acc[dt][1] * inv;
            o.z = acc[dt][2] * inv; o.w = acc[dt][3] * inv;
            *(float4*)(op + dt * 16) = o;
        }
    } else {
        _Float16* op = part + bid * 16384 + w * 2048 + l * 4;
#pragma unroll
        for (int dt = 0; dt < 8; ++dt) {
            half4v h;
#pragma unroll
            for (int r = 0; r < 4; ++r) h[r] = (_Float16)(acc[dt][r] * inv);
            *(half4v*)(op + dt * 256) = h;
        }
        if (l < 16) {
            int ridx = bid * 128 + w * 16 + l;
            float2 st; st.x = mrow; st.y = lrow;
            *(float2*)(&stats[ridx * 2]) = st;
        }
    }
#undef GLOAD_TILE
}

// ---------------- kernel 3: combine split-KV partials (qt >= 2, nc in [2,8]) ----------------
__global__ __launch_bounds__(256) void comb_k(const _Float16* __restrict__ part,
                                              const float* __restrict__ stats,
                                              float* __restrict__ out) {
    int bid = blockIdx.x;
    int b = bid & 7, qt = 2 + (bid >> 3);
    int h = qt >> 1;
    int nc = h + 1;
    int u0 = qt + h * (h - 1) + (qt & 1) * h;
    int t = threadIdx.x;
    int row = t >> 1, g = t & 1;
    int w = row >> 4, q16 = row & 15;

    float mstar = -1e30f, mv[8], lv[8];
#pragma unroll
    for (int cc = 0; cc < 8; ++cc) {
        if (cc < nc) {
            int sidx = (((u0 + cc) << 3) + b) * 128 + row;
            mv[cc] = stats[sidx * 2];
            lv[cc] = stats[sidx * 2 + 1];
            mstar = fmaxf(mstar, mv[cc]);
        }
    }
    float den = 0.f, wc[8];
#pragma unroll
    for (int cc = 0; cc < 8; ++cc) {
        if (cc < nc) { wc[cc] = __expf(mv[cc] - mstar) * lv[cc]; den += wc[cc]; }
        else wc[cc] = 0.f;
    }
    float a[64] = {};
#pragma unroll
    for (int cc = 0; cc < 8; ++cc) {
        if (cc < nc) {
            const _Float16* pp = part + ((((u0 + cc) << 3) + b) * 16384) + w * 2048;
            float wcc = wc[cc];
#pragma unroll
            for (int dd = 0; dd < 4; ++dd) {
                int dt = 4 * g + dd;
#pragma unroll
                for (int fq = 0; fq < 4; ++fq) {
                    half4v hh = *(const half4v*)(pp + dt * 256 + (fq * 16 + q16) * 4);
#pragma unroll
                    for (int r = 0; r < 4; ++r)
                        a[dd * 16 + fq * 4 + r] += wcc * (float)hh[r];
                }
            }
        }
    }
    float id = 1.0f / den;
    float* op = out + (b * 2048 + qt * 128 + row) * 128 + g * 64;
#pragma unroll
    for (int uu = 0; uu < 16; ++uu) {
        float4 o;
        o.x = a[uu * 4]     * id;
        o.y = a[uu * 4 + 1] * id;
        o.z = a[uu * 4 + 2] * id;
        o.w = a[uu * 4 + 3] * id;
        *(float4*)(op + uu * 4) = o;
    }
}

extern "C" void kernel_launch(void* const* d_in, const int* in_sizes, int n_in,
                              void* d_out, int out_size, void* d_ws, size_t ws_size,
                              hipStream_t stream) {
    const float* x  = (const float*)d_in[0];
    const float* wq = (const float*)d_in[1];
    const float* wk = (const float*)d_in[2];
    const float* wv = (const float*)d_in[3];

    char* ws = (char*)d_ws;
    _Float16* wh   = (_Float16*)(ws);                    // 768 KB
    _Float16* qhp  = (_Float16*)(ws + (1u  << 20));      // 4 MB
    _Float16* khp  = (_Float16*)(ws + (5u  << 20));      // 4 MB
    _Float16* vtp  = (_Float16*)(ws + (9u  << 20));      // 4 MB
    _Float16* part = (_Float16*)(ws + (13u << 20));      // 576*32KB = 18 MB
    float*    stat = (float*)   (ws + (32u << 20));      // 590 KB

    wconv_k<<<192, 256, 0, stream>>>(wq, wk, wv, wh);
    qkv_k<<<768, 256, 0, stream>>>(x, wh, qhp, khp, vtp);
    attn_k<<<576, 512, 0, stream>>>(qhp, khp, vtp, part, stat, (float*)d_out);
    comb_k<<<112, 256, 0, stream>>>(part, stat, (float*)d_out);
}

// Round 19
// 84.403 us; speedup vs baseline: 1.1271x; 1.1112x over previous
//
#include <hip/hip_runtime.h>
#include <hip/hip_fp16.h>

typedef _Float16 half8  __attribute__((ext_vector_type(8)));
typedef _Float16 half4v __attribute__((ext_vector_type(4)));
typedef float    f32x4  __attribute__((ext_vector_type(4)));

#define MFMA_F16 __builtin_amdgcn_mfma_f32_16x16x32_f16

#define BAR_LDS() asm volatile("s_waitcnt lgkmcnt(0)\n\ts_barrier" ::: "memory")
#define BAR_VM()  asm volatile("s_waitcnt vmcnt(0)\n\ts_barrier" ::: "memory")

__device__ __forceinline__ unsigned pack_f16(float a, float b) {
    union { __fp16 h __attribute__((ext_vector_type(2))); unsigned u; } cv;
    cv.h = __builtin_amdgcn_cvt_pkrtz(a, b);
    return cv.u;
}

__device__ __forceinline__ void gload16(const _Float16* g, _Float16* l) {
    __builtin_amdgcn_global_load_lds((const __attribute__((address_space(1))) void*)g,
                                     (__attribute__((address_space(3))) void*)l, 16, 0, 0);
}

// ---------------- kernel 0: convert x and W_q|W_k|W_v to f16 ----------------
// x[16M f32] -> xh[16M f16]; W[384K f32] -> wh. 8384 blocks x 256 thr, 8 elems/thread.
__global__ __launch_bounds__(256) void cvt_k(const float* __restrict__ x,
                                             const float* __restrict__ wq,
                                             const float* __restrict__ wk,
                                             const float* __restrict__ wv,
                                             _Float16* __restrict__ xh,
                                             _Float16* __restrict__ wh) {
    int i = (blockIdx.x * 256 + threadIdx.x) * 8;
    const float* src;
    _Float16* dst;
    int off;
    if (i < 16777216) { src = x; dst = xh; off = i; }
    else {
        int j = i - 16777216;
        dst = wh; off = j;
        if (j < 131072)      { src = wq; }
        else if (j < 262144) { src = wk; off = j; }
        else                 { src = wv; off = j; }
        // adjust source offset per segment
        if (j < 131072)      { src = wq; }
        else if (j < 262144) { src = wk; j -= 131072; }
        else                 { src = wv; j -= 262144; }
        float4 a = *(const float4*)(src + j);
        float4 b = *(const float4*)(src + j + 4);
        half8 h;
        h[0]=(_Float16)a.x; h[1]=(_Float16)a.y; h[2]=(_Float16)a.z; h[3]=(_Float16)a.w;
        h[4]=(_Float16)b.x; h[5]=(_Float16)b.y; h[6]=(_Float16)b.z; h[7]=(_Float16)b.w;
        *(half8*)(dst + off) = h;
        return;
    }
    float4 a = *(const float4*)(src + off);
    float4 b = *(const float4*)(src + off + 4);
    half8 h;
    h[0]=(_Float16)a.x; h[1]=(_Float16)a.y; h[2]=(_Float16)a.z; h[3]=(_Float16)a.w;
    h[4]=(_Float16)b.x; h[5]=(_Float16)b.y; h[6]=(_Float16)b.z; h[7]=(_Float16)b.w;
    *(half8*)(dst + off) = h;
}

// ---------------- kernel 1: fused QKV projection (f16 x, global_load_lds staging) ----------------
// grid 768, XCD-pinned. Staging: gload_lds width=16, LDS dest linear, XOR swizzle on the
// per-lane GLOBAL source (rule #21). No reg round-trip, no cvt, no ds_write. 32 KB LDS.
__global__ __launch_bounds__(256, 4) void qkv_k(const _Float16* __restrict__ xh,
                                                const _Float16* __restrict__ wh,
                                                _Float16* __restrict__ qh,
                                                _Float16* __restrict__ kh,
                                                _Float16* __restrict__ vth) {
    __shared__ _Float16 xs[2][64 * 128];   // swizzled via source perm; rows 256B
    const int tid = threadIdx.x;
    const int w = tid >> 6, l = tid & 63;
    const int fr = l & 15, fq = l >> 4;
    const int bid = blockIdx.x;
    const int xcd = bid & 7;
    const int slot = bid >> 3;
    const int rb = (slot / 3) * 8 + xcd;
    const int cb = slot % 3;
    const int row0 = rb * 64;
    const int c0 = cb * 128 + w * 32;
    const int xwk = (fr & 7) << 4;         // af read XOR key

    // staging lane constants: issue i covers LDS bytes w*4096 + i*1024 + l*16
    int srow[4], scol[4];
#pragma unroll
    for (int i = 0; i < 4; ++i) {
        int ob = w * 4096 + i * 1024 + l * 16;
        srow[i] = ob >> 8;
        scol[i] = ((ob & 255) ^ ((srow[i] & 7) << 4)) >> 1;
    }
    const _Float16* wgb = wh + (c0 + fr) * 1024 + fq * 8;

    f32x4 acc[4][2] = {};
    half8 wf[4][2];                        // W ring: slot ss&3 holds substep ss

#define GLX(kt, bb) do {                                                                  \
    _Pragma("unroll")                                                                     \
    for (int i = 0; i < 4; ++i)                                                           \
        gload16(xh + (row0 + srow[i]) * 1024 + (kt) * 128 + scol[i],                      \
                &xs[bb][0] + w * 2048 + i * 512);                                         \
    } while (0)

    // prologue: W slots 0..2; x tile0 -> LDS0; barrier; tile1 -> LDS1
#pragma unroll
    for (int ss = 0; ss < 3; ++ss)
#pragma unroll
        for (int nf = 0; nf < 2; ++nf)
            wf[ss][nf] = *(const half8*)(wgb + nf * 16384 + ss * 32);
    GLX(0, 0);
    BAR_VM();
    GLX(1, 1);

    int cur = 0;
    for (int kt = 0; kt < 8; ++kt) {
#pragma unroll
        for (int s = 0; s < 4; ++s) {
            const int ss = kt * 4 + s;
            if (ss + 3 < 32) {
#pragma unroll
                for (int nf = 0; nf < 2; ++nf)
                    wf[(ss + 3) & 3][nf] = *(const half8*)(wgb + nf * 16384 + (ss + 3) * 32);
            }
            half8 af[4];
#pragma unroll
            for (int mf = 0; mf < 4; ++mf) {
                const char* rp = (const char*)(&xs[cur][0]) + (mf * 16 + fr) * 256;
                af[mf] = *(const half8*)(rp + ((s * 64 + fq * 16) ^ xwk));
            }
#pragma unroll
            for (int mf = 0; mf < 4; ++mf)
#pragma unroll
                for (int nf = 0; nf < 2; ++nf)
                    acc[mf][nf] = MFMA_F16(af[mf], wf[ss & 3][nf], acc[mf][nf], 0, 0, 0);
        }
        BAR_VM();                          // tile kt+1 landed (issued a full iter ago)
        if (kt + 2 < 8) GLX(kt + 2, cur);  // cur's readers all passed the barrier
        cur ^= 1;
    }
#undef GLX

    // epilogue: block-uniform destination (cb 0->Q, 1->K, 2->V-permuted)
#pragma unroll
    for (int nf = 0; nf < 2; ++nf) {
        int n0 = c0 + nf * 16 + fr;
#pragma unroll
        for (int mf = 0; mf < 4; ++mf) {
            int mb = row0 + mf * 16 + fq * 4;
            if (cb == 0) {
#pragma unroll
                for (int r = 0; r < 4; ++r) qh[(mb + r) * 128 + n0] = (_Float16)acc[mf][nf][r];
            } else if (cb == 1) {
#pragma unroll
                for (int r = 0; r < 4; ++r) kh[(mb + r) * 128 + (n0 - 128)] = (_Float16)acc[mf][nf][r];
            } else {
                half4v pv;
#pragma unroll
                for (int r = 0; r < 4; ++r) pv[r] = (_Float16)acc[mf][nf][r];
                int t = mb & 2047;
                int tl = t & 63;
                int tp = (t & ~63) | (tl & 35) | ((tl & 12) << 1) | ((tl & 16) >> 2);
                *(half4v*)(&vth[((mb >> 11) * 128 + (n0 - 256)) * 2048 + tp]) = pv;
            }
        }
    }
}

// ---------------- kernel 2: causal flash attention (unchanged from R18) ----------------
__global__ __launch_bounds__(512, 4) void attn_k(const _Float16* __restrict__ qh,
                                                 const _Float16* __restrict__ kh,
                                                 const _Float16* __restrict__ vth,
                                                 _Float16* __restrict__ part,
                                                 float* __restrict__ stats,
                                                 float* __restrict__ out) {
    __shared__ _Float16 ks[2][32 * 128];
    __shared__ _Float16 vs[2][128 * 32];

    int bid = blockIdx.x;
    int b = bid & 7;
    int u = bid >> 3;
    int qt, c;
    {
        int idx = u;
        qt = 0;
        for (;;) { int nc = (qt >> 1) + 1; if (idx < nc) break; idx -= nc; ++qt; }
        c = idx;
    }
    int j0 = c * 8;
    int jmax = 4 * qt + 4;
    int j1 = j0 + 8 < jmax ? j0 + 8 : jmax;

    int tid = threadIdx.x, w = tid >> 6, l = tid & 63;
    int fr = l & 15, fq = l >> 4;
    int xw = (fr & 7) << 4;
    int xv = (fr & 3) << 4;

    const int kr  = tid >> 4;
    const int kc  = (tid & 15) ^ (kr & 7);
    const int vdd = tid >> 2;
    const int vc  = (tid & 3) ^ (vdd & 3);

    half8 qf[4];
    const _Float16* qp = qh + ((b * 2048 + qt * 128 + w * 16 + fr) << 7);
#pragma unroll
    for (int cc = 0; cc < 4; ++cc) qf[cc] = *(const half8*)(qp + cc * 32 + fq * 8);

#define GLOAD_TILE(j, bb) do {                                                            \
    gload16(kh + (((b << 11) + ((j) << 5) + kr) << 7) + kc * 8, &ks[bb][0] + w * 512);    \
    gload16(vth + (((b << 7) + vdd) << 11) + ((j) << 5) + vc * 8, &vs[bb][0] + w * 512);  \
    } while (0)

    f32x4 acc[8] = {};
    float mrow = -1e30f, lrow = 0.0f;

    GLOAD_TILE(j0, 0);
    BAR_VM();
    if (j0 + 1 < j1) GLOAD_TILE(j0 + 1, 1);

    int cur = 0;
    for (int j = j0; j < j1; ++j) {
        const char* ksb = (const char*)(ks[cur]);
        const char* vsb = (const char*)(vs[cur]);

        f32x4 s[2] = {};
        __builtin_amdgcn_s_setprio(1);
#pragma unroll
        for (int n = 0; n < 2; ++n) {
            const char* krow = ksb + (n * 16 + fr) * 256;
#pragma unroll
            for (int cc = 0; cc < 4; ++cc) {
                half8 kf = *(const half8*)(krow + ((cc * 64 + fq * 16) ^ xw));
                s[n] = MFMA_F16(kf, qf[cc], s[n], 0, 0, 0);
            }
        }
        __builtin_amdgcn_s_setprio(0);
        const float sc = 0.088388347648318447f;  // 1/sqrt(128)
        if (j >= 4 * qt) {
            int koff = (j - 4 * qt) << 5;
            int qrow = w * 16 + fr;
#pragma unroll
            for (int n = 0; n < 2; ++n)
#pragma unroll
                for (int r = 0; r < 4; ++r) {
                    int kcol = koff + n * 16 + fq * 4 + r;
                    float v = s[n][r] * sc;
                    s[n][r] = (kcol > qrow) ? -1e30f : v;
                }
        } else {
#pragma unroll
            for (int n = 0; n < 2; ++n)
#pragma unroll
                for (int r = 0; r < 4; ++r) s[n][r] *= sc;
        }

        // online softmax with defer-max (T13)
        float pmax = s[0][0];
#pragma unroll
        for (int n = 0; n < 2; ++n)
#pragma unroll
            for (int r = 0; r < 4; ++r) pmax = fmaxf(pmax, s[n][r]);
        float al = 1.0f;
        if (!__all(pmax - mrow <= 8.0f)) {
            float mx = pmax;
            mx = fmaxf(mx, __shfl_xor(mx, 16));
            mx = fmaxf(mx, __shfl_xor(mx, 32));
            float nm = fmaxf(mrow, mx);
            al = __expf(mrow - nm);
            mrow = nm;
#pragma unroll
            for (int dt = 0; dt < 8; ++dt)
#pragma unroll
                for (int r = 0; r < 4; ++r) acc[dt][r] *= al;
        }
        float rs = 0.f;
#pragma unroll
        for (int n = 0; n < 2; ++n)
#pragma unroll
            for (int r = 0; r < 4; ++r) {
                float p = __expf(s[n][r] - mrow);
                s[n][r] = p;
                rs += p;
            }
        rs += __shfl_xor(rs, 16);
        rs += __shfl_xor(rs, 32);
        lrow = lrow * al + rs;

        union { unsigned u[4]; half8 h; } pb;
        pb.u[0] = pack_f16(s[0][0], s[0][1]);
        pb.u[1] = pack_f16(s[0][2], s[0][3]);
        pb.u[2] = pack_f16(s[1][0], s[1][1]);
        pb.u[3] = pack_f16(s[1][2], s[1][3]);

        __builtin_amdgcn_s_setprio(1);
#pragma unroll
        for (int dt = 0; dt < 8; ++dt) {
            const char* vrow = vsb + (dt * 16 + fr) * 64;
            half8 vf = *(const half8*)(vrow + ((fq * 16) ^ xv));
            acc[dt] = MFMA_F16(vf, pb.h, acc[dt], 0, 0, 0);
        }
        __builtin_amdgcn_s_setprio(0);

        BAR_VM();
        if (j + 2 < j1) GLOAD_TILE(j + 2, cur);
        cur ^= 1;
    }

    float inv = 1.0f / lrow;

    if (qt < 2) {
        float* op = out + ((b * 2048 + qt * 128 + w * 16 + fr) << 7) + fq * 4;
#pragma unroll
        for (int dt = 0; dt < 8; ++dt) {
            float4 o;
            o.x = acc[dt][0] * inv; o.y = acc[dt][1] * inv;
            o.z = acc[dt][2] * inv; o.w = acc[dt][3] * inv;
            *(float4*)(op + dt * 16) = o;
        }
    } else {
        _Float16* op = part + bid * 16384 + w * 2048 + l * 4;
#pragma unroll
        for (int dt = 0; dt < 8; ++dt) {
            half4v h;
#pragma unroll
            for (int r = 0; r < 4; ++r) h[r] = (_Float16)(acc[dt][r] * inv);
            *(half4v*)(op + dt * 256) = h;
        }
        if (l < 16) {
            int ridx = bid * 128 + w * 16 + l;
            float2 st; st.x = mrow; st.y = lrow;
            *(float2*)(&stats[ridx * 2]) = st;
        }
    }
#undef GLOAD_TILE
}

// ---------------- kernel 3: combine split-KV partials (4x parallelism) ----------------
// 448 blocks: b = bid&7; rest = bid>>3: qt = 2 + rest>>2, rh = rest&3 (32-row quarter).
// thread: row = rh*32 + (t>>3), d-chunk g = t&7 (16 d).
__global__ __launch_bounds__(256) void comb_k(const _Float16* __restrict__ part,
                                              const float* __restrict__ stats,
                                              float* __restrict__ out) {
    int bid = blockIdx.x;
    int b = bid & 7;
    int rest = bid >> 3;
    int qt = 2 + (rest >> 2);
    int rh = rest & 3;
    int h = qt >> 1;
    int nc = h + 1;
    int u0 = qt + h * (h - 1) + (qt & 1) * h;
    int t = threadIdx.x;
    int row = rh * 32 + (t >> 3), g = t & 7;
    int w = row >> 4, q16 = row & 15;

    float mstar = -1e30f, mv[8], lv[8];
#pragma unroll
    for (int cc = 0; cc < 8; ++cc) {
        if (cc < nc) {
            int sidx = (((u0 + cc) << 3) + b) * 128 + row;
            mv[cc] = stats[sidx * 2];
            lv[cc] = stats[sidx * 2 + 1];
            mstar = fmaxf(mstar, mv[cc]);
        }
    }
    float den = 0.f, wc[8];
#pragma unroll
    for (int cc = 0; cc < 8; ++cc) {
        if (cc < nc) { wc[cc] = __expf(mv[cc] - mstar) * lv[cc]; den += wc[cc]; }
        else wc[cc] = 0.f;
    }
    float a[16] = {};
#pragma unroll
    for (int cc = 0; cc < 8; ++cc) {
        if (cc < nc) {
            const _Float16* pp = part + ((((u0 + cc) << 3) + b) * 16384) + w * 2048 + g * 256;
            float wcc = wc[cc];
#pragma unroll
            for (int fq = 0; fq < 4; ++fq) {
                half4v hh = *(const half4v*)(pp + (fq * 16 + q16) * 4);
#pragma unroll
                for (int r = 0; r < 4; ++r)
                    a[fq * 4 + r] += wcc * (float)hh[r];
            }
        }
    }
    float id = 1.0f / den;
    float* op = out + (b * 2048 + qt * 128 + row) * 128 + g * 16;
#pragma unroll
    for (int uu = 0; uu < 4; ++uu) {
        float4 o;
        o.x = a[uu * 4]     * id;
        o.y = a[uu * 4 + 1] * id;
        o.z = a[uu * 4 + 2] * id;
        o.w = a[uu * 4 + 3] * id;
        *(float4*)(op + uu * 4) = o;
    }
}

extern "C" void kernel_launch(void* const* d_in, const int* in_sizes, int n_in,
                              void* d_out, int out_size, void* d_ws, size_t ws_size,
                              hipStream_t stream) {
    const float* x  = (const float*)d_in[0];
    const float* wq = (const float*)d_in[1];
    const float* wk = (const float*)d_in[2];
    const float* wv = (const float*)d_in[3];

    char* ws = (char*)d_ws;
    _Float16* wh   = (_Float16*)(ws);                    // 768 KB
    _Float16* qhp  = (_Float16*)(ws + (1u  << 20));      // 4 MB
    _Float16* khp  = (_Float16*)(ws + (5u  << 20));      // 4 MB
    _Float16* vtp  = (_Float16*)(ws + (9u  << 20));      // 4 MB
    _Float16* part = (_Float16*)(ws + (13u << 20));      // 576*32KB = 18 MB
    float*    stat = (float*)   (ws + (32u << 20));      // 590 KB
    _Float16* xhp  = (_Float16*)(ws + (34u << 20));      // 32 MB

    cvt_k<<<8384, 256, 0, stream>>>(x, wq, wk, wv, xhp, wh);
    qkv_k<<<768, 256, 0, stream>>>(xhp, wh, qhp, khp, vtp);
    attn_k<<<576, 512, 0, stream>>>(qhp, khp, vtp, part, stat, (float*)d_out);
    comb_k<<<448, 256, 0, stream>>>(part, stat, (float*)d_out);
}

// Round 20
// 78.942 us; speedup vs baseline: 1.2050x; 1.0692x over previous
//
#include <hip/hip_runtime.h>
#include <hip/hip_fp16.h>

typedef _Float16 half8  __attribute__((ext_vector_type(8)));
typedef _Float16 half4v __attribute__((ext_vector_type(4)));
typedef float    f32x4  __attribute__((ext_vector_type(4)));

#define MFMA_F16 __builtin_amdgcn_mfma_f32_16x16x32_f16

#define BAR_LDS() asm volatile("s_waitcnt lgkmcnt(0)\n\ts_barrier" ::: "memory")
#define BAR_VM()  asm volatile("s_waitcnt vmcnt(0)\n\ts_barrier" ::: "memory")

__device__ __forceinline__ unsigned pack_f16(float a, float b) {
    union { __fp16 h __attribute__((ext_vector_type(2))); unsigned u; } cv;
    cv.h = __builtin_amdgcn_cvt_pkrtz(a, b);
    return cv.u;
}

__device__ __forceinline__ void gload16(const void* g, void* l) {
    __builtin_amdgcn_global_load_lds((const __attribute__((address_space(1))) void*)g,
                                     (__attribute__((address_space(3))) void*)l, 16, 0, 0);
}

// ---------------- kernel 0: W_q|W_k|W_v f32 -> concat f16 [384][1024] ----------------
__global__ __launch_bounds__(256) void wconv_k(const float* __restrict__ wq,
                                               const float* __restrict__ wk,
                                               const float* __restrict__ wv,
                                               _Float16* __restrict__ wh) {
    int i = (blockIdx.x * 256 + threadIdx.x) * 8;
    const float* src; int off;
    if (i < 131072)      { src = wq; off = i; }
    else if (i < 262144) { src = wk; off = i - 131072; }
    else                 { src = wv; off = i - 262144; }
    float4 a = *(const float4*)(src + off);
    float4 b = *(const float4*)(src + off + 4);
    half8 h;
    h[0]=(_Float16)a.x; h[1]=(_Float16)a.y; h[2]=(_Float16)a.z; h[3]=(_Float16)a.w;
    h[4]=(_Float16)b.x; h[5]=(_Float16)b.y; h[6]=(_Float16)b.z; h[7]=(_Float16)b.w;
    *(half8*)(wh + i) = h;
}

// ---------------- kernel 1: fused QKV projection (f32 x staged via global_load_lds) ----------------
// grid 768, XCD-pinned. k-step 64: x tile 64r x 64k f32 = 16KB, dbuf = 32KB LDS.
// Staging: gload_lds width=16, linear LDS dest, XOR swizzle on the per-lane GLOBAL
// source (rule #21). f32->f16 convert happens on the LDS READ (4 cvt_pk per fragment).
__global__ __launch_bounds__(256, 4) void qkv_k(const float* __restrict__ x,
                                                const _Float16* __restrict__ wh,
                                                _Float16* __restrict__ qh,
                                                _Float16* __restrict__ kh,
                                                _Float16* __restrict__ vth) {
    __shared__ float xs[2][64 * 64];       // 16KB per buffer; rows = 256B
    const int tid = threadIdx.x;
    const int w = tid >> 6, l = tid & 63;
    const int fr = l & 15, fq = l >> 4;
    const int bid = blockIdx.x;
    const int xcd = bid & 7;
    const int slot = bid >> 3;
    const int rb = (slot / 3) * 8 + xcd;
    const int cb = slot % 3;
    const int row0 = rb * 64;
    const int c0 = cb * 128 + w * 32;
    const int xwk = (fr & 7) << 4;         // fragment-read XOR key

    // staging lane constants: issue i covers LDS bytes i*4096 + w*1024 + l*16
    int srow[4], scolB[4];
#pragma unroll
    for (int i = 0; i < 4; ++i) {
        int ob = i * 4096 + w * 1024 + l * 16;
        srow[i]  = ob >> 8;
        scolB[i] = (ob & 255) ^ ((srow[i] & 7) << 4);   // swizzled byte-in-row
    }
    const _Float16* wgb = wh + (c0 + fr) * 1024 + fq * 8;

    f32x4 acc[4][2] = {};
    half8 wf[2][2];                        // W ring: slot ss&1

#define GLX(kt, bb) do {                                                                  \
    _Pragma("unroll")                                                                     \
    for (int i = 0; i < 4; ++i)                                                           \
        gload16(x + (row0 + srow[i]) * 1024 + (kt) * 64 + (scolB[i] >> 2),                \
                (char*)(&xs[bb][0]) + i * 4096 + w * 1024);                               \
    } while (0)

    // prologue: W substep 0; x tile0 -> LDS0; barrier; tile1 -> LDS1
#pragma unroll
    for (int nf = 0; nf < 2; ++nf) wf[0][nf] = *(const half8*)(wgb + nf * 16384);
    GLX(0, 0);
    BAR_VM();
    GLX(1, 1);

    int cur = 0;
    for (int kt = 0; kt < 16; ++kt) {
#pragma unroll
        for (int s = 0; s < 2; ++s) {
            const int ss = kt * 2 + s;
            if (ss + 1 < 32) {
#pragma unroll
                for (int nf = 0; nf < 2; ++nf)
                    wf[(ss + 1) & 1][nf] = *(const half8*)(wgb + nf * 16384 + (ss + 1) * 32);
            }
            half8 af[4];
#pragma unroll
            for (int mf = 0; mf < 4; ++mf) {
                const char* rp = (const char*)(&xs[cur][0]) + (mf * 16 + fr) * 256;
                const int X = s * 128 + fq * 32;
                float4 a0 = *(const float4*)(rp + (X ^ xwk));
                float4 a1 = *(const float4*)(rp + ((X + 16) ^ xwk));
                union { unsigned u[4]; half8 h; } cv;
                cv.u[0] = pack_f16(a0.x, a0.y);
                cv.u[1] = pack_f16(a0.z, a0.w);
                cv.u[2] = pack_f16(a1.x, a1.y);
                cv.u[3] = pack_f16(a1.z, a1.w);
                af[mf] = cv.h;
            }
#pragma unroll
            for (int mf = 0; mf < 4; ++mf)
#pragma unroll
                for (int nf = 0; nf < 2; ++nf)
                    acc[mf][nf] = MFMA_F16(af[mf], wf[ss & 1][nf], acc[mf][nf], 0, 0, 0);
        }
        BAR_VM();                          // tile kt+1 landed (issued a full tile ago)
        if (kt + 2 < 16) GLX(kt + 2, cur); // cur's readers all passed the barrier
        cur ^= 1;
    }
#undef GLX

    // epilogue: block-uniform destination (cb 0->Q, 1->K, 2->V-permuted)
#pragma unroll
    for (int nf = 0; nf < 2; ++nf) {
        int n0 = c0 + nf * 16 + fr;
#pragma unroll
        for (int mf = 0; mf < 4; ++mf) {
            int mb = row0 + mf * 16 + fq * 4;
            if (cb == 0) {
#pragma unroll
                for (int r = 0; r < 4; ++r) qh[(mb + r) * 128 + n0] = (_Float16)acc[mf][nf][r];
            } else if (cb == 1) {
#pragma unroll
                for (int r = 0; r < 4; ++r) kh[(mb + r) * 128 + (n0 - 128)] = (_Float16)acc[mf][nf][r];
            } else {
                half4v pv;
#pragma unroll
                for (int r = 0; r < 4; ++r) pv[r] = (_Float16)acc[mf][nf][r];
                int t = mb & 2047;
                int tl = t & 63;
                int tp = (t & ~63) | (tl & 35) | ((tl & 12) << 1) | ((tl & 16) >> 2);
                *(half4v*)(&vth[((mb >> 11) * 128 + (n0 - 256)) * 2048 + tp]) = pv;
            }
        }
    }
}

// ---------------- kernel 2: causal flash attention (unchanged from R19) ----------------
__global__ __launch_bounds__(512, 4) void attn_k(const _Float16* __restrict__ qh,
                                                 const _Float16* __restrict__ kh,
                                                 const _Float16* __restrict__ vth,
                                                 _Float16* __restrict__ part,
                                                 float* __restrict__ stats,
                                                 float* __restrict__ out) {
    __shared__ _Float16 ks[2][32 * 128];
    __shared__ _Float16 vs[2][128 * 32];

    int bid = blockIdx.x;
    int b = bid & 7;
    int u = bid >> 3;
    int qt, c;
    {
        int idx = u;
        qt = 0;
        for (;;) { int nc = (qt >> 1) + 1; if (idx < nc) break; idx -= nc; ++qt; }
        c = idx;
    }
    int j0 = c * 8;
    int jmax = 4 * qt + 4;
    int j1 = j0 + 8 < jmax ? j0 + 8 : jmax;

    int tid = threadIdx.x, w = tid >> 6, l = tid & 63;
    int fr = l & 15, fq = l >> 4;
    int xw = (fr & 7) << 4;
    int xv = (fr & 3) << 4;

    const int kr  = tid >> 4;
    const int kc  = (tid & 15) ^ (kr & 7);
    const int vdd = tid >> 2;
    const int vc  = (tid & 3) ^ (vdd & 3);

    half8 qf[4];
    const _Float16* qp = qh + ((b * 2048 + qt * 128 + w * 16 + fr) << 7);
#pragma unroll
    for (int cc = 0; cc < 4; ++cc) qf[cc] = *(const half8*)(qp + cc * 32 + fq * 8);

#define GLOAD_TILE(j, bb) do {                                                            \
    gload16(kh + (((b << 11) + ((j) << 5) + kr) << 7) + kc * 8, &ks[bb][0] + w * 512);    \
    gload16(vth + (((b << 7) + vdd) << 11) + ((j) << 5) + vc * 8, &vs[bb][0] + w * 512);  \
    } while (0)

    f32x4 acc[8] = {};
    float mrow = -1e30f, lrow = 0.0f;

    GLOAD_TILE(j0, 0);
    BAR_VM();
    if (j0 + 1 < j1) GLOAD_TILE(j0 + 1, 1);

    int cur = 0;
    for (int j = j0; j < j1; ++j) {
        const char* ksb = (const char*)(ks[cur]);
        const char* vsb = (const char*)(vs[cur]);

        f32x4 s[2] = {};
        __builtin_amdgcn_s_setprio(1);
#pragma unroll
        for (int n = 0; n < 2; ++n) {
            const char* krow = ksb + (n * 16 + fr) * 256;
#pragma unroll
            for (int cc = 0; cc < 4; ++cc) {
                half8 kf = *(const half8*)(krow + ((cc * 64 + fq * 16) ^ xw));
                s[n] = MFMA_F16(kf, qf[cc], s[n], 0, 0, 0);
            }
        }
        __builtin_amdgcn_s_setprio(0);
        const float sc = 0.088388347648318447f;  // 1/sqrt(128)
        if (j >= 4 * qt) {
            int koff = (j - 4 * qt) << 5;
            int qrow = w * 16 + fr;
#pragma unroll
            for (int n = 0; n < 2; ++n)
#pragma unroll
                for (int r = 0; r < 4; ++r) {
                    int kcol = koff + n * 16 + fq * 4 + r;
                    float v = s[n][r] * sc;
                    s[n][r] = (kcol > qrow) ? -1e30f : v;
                }
        } else {
#pragma unroll
            for (int n = 0; n < 2; ++n)
#pragma unroll
                for (int r = 0; r < 4; ++r) s[n][r] *= sc;
        }

        // online softmax with defer-max (T13)
        float pmax = s[0][0];
#pragma unroll
        for (int n = 0; n < 2; ++n)
#pragma unroll
            for (int r = 0; r < 4; ++r) pmax = fmaxf(pmax, s[n][r]);
        float al = 1.0f;
        if (!__all(pmax - mrow <= 8.0f)) {
            float mx = pmax;
            mx = fmaxf(mx, __shfl_xor(mx, 16));
            mx = fmaxf(mx, __shfl_xor(mx, 32));
            float nm = fmaxf(mrow, mx);
            al = __expf(mrow - nm);
            mrow = nm;
#pragma unroll
            for (int dt = 0; dt < 8; ++dt)
#pragma unroll
                for (int r = 0; r < 4; ++r) acc[dt][r] *= al;
        }
        float rs = 0.f;
#pragma unroll
        for (int n = 0; n < 2; ++n)
#pragma unroll
            for (int r = 0; r < 4; ++r) {
                float p = __expf(s[n][r] - mrow);
                s[n][r] = p;
                rs += p;
            }
        rs += __shfl_xor(rs, 16);
        rs += __shfl_xor(rs, 32);
        lrow = lrow * al + rs;

        union { unsigned u[4]; half8 h; } pb;
        pb.u[0] = pack_f16(s[0][0], s[0][1]);
        pb.u[1] = pack_f16(s[0][2], s[0][3]);
        pb.u[2] = pack_f16(s[1][0], s[1][1]);
        pb.u[3] = pack_f16(s[1][2], s[1][3]);

        __builtin_amdgcn_s_setprio(1);
#pragma unroll
        for (int dt = 0; dt < 8; ++dt) {
            const char* vrow = vsb + (dt * 16 + fr) * 64;
            half8 vf = *(const half8*)(vrow + ((fq * 16) ^ xv));
            acc[dt] = MFMA_F16(vf, pb.h, acc[dt], 0, 0, 0);
        }
        __builtin_amdgcn_s_setprio(0);

        BAR_VM();
        if (j + 2 < j1) GLOAD_TILE(j + 2, cur);
        cur ^= 1;
    }

    float inv = 1.0f / lrow;

    if (qt < 2) {
        float* op = out + ((b * 2048 + qt * 128 + w * 16 + fr) << 7) + fq * 4;
#pragma unroll
        for (int dt = 0; dt < 8; ++dt) {
            float4 o;
            o.x = acc[dt][0] * inv; o.y = acc[dt][1] * inv;
            o.z = acc[dt][2] * inv; o.w = acc[dt][3] * inv;
            *(float4*)(op + dt * 16) = o;
        }
    } else {
        _Float16* op = part + bid * 16384 + w * 2048 + l * 4;
#pragma unroll
        for (int dt = 0; dt < 8; ++dt) {
            half4v h;
#pragma unroll
            for (int r = 0; r < 4; ++r) h[r] = (_Float16)(acc[dt][r] * inv);
            *(half4v*)(op + dt * 256) = h;
        }
        if (l < 16) {
            int ridx = bid * 128 + w * 16 + l;
            float2 st; st.x = mrow; st.y = lrow;
            *(float2*)(&stats[ridx * 2]) = st;
        }
    }
#undef GLOAD_TILE
}

// ---------------- kernel 3: combine split-KV partials (unchanged from R19) ----------------
__global__ __launch_bounds__(256) void comb_k(const _Float16* __restrict__ part,
                                              const float* __restrict__ stats,
                                              float* __restrict__ out) {
    int bid = blockIdx.x;
    int b = bid & 7;
    int rest = bid >> 3;
    int qt = 2 + (rest >> 2);
    int rh = rest & 3;
    int h = qt >> 1;
    int nc = h + 1;
    int u0 = qt + h * (h - 1) + (qt & 1) * h;
    int t = threadIdx.x;
    int row = rh * 32 + (t >> 3), g = t & 7;
    int w = row >> 4, q16 = row & 15;

    float mstar = -1e30f, mv[8], lv[8];
#pragma unroll
    for (int cc = 0; cc < 8; ++cc) {
        if (cc < nc) {
            int sidx = (((u0 + cc) << 3) + b) * 128 + row;
            mv[cc] = stats[sidx * 2];
            lv[cc] = stats[sidx * 2 + 1];
            mstar = fmaxf(mstar, mv[cc]);
        }
    }
    float den = 0.f, wc[8];
#pragma unroll
    for (int cc = 0; cc < 8; ++cc) {
        if (cc < nc) { wc[cc] = __expf(mv[cc] - mstar) * lv[cc]; den += wc[cc]; }
        else wc[cc] = 0.f;
    }
    float a[16] = {};
#pragma unroll
    for (int cc = 0; cc < 8; ++cc) {
        if (cc < nc) {
            const _Float16* pp = part + ((((u0 + cc) << 3) + b) * 16384) + w * 2048 + g * 256;
            float wcc = wc[cc];
#pragma unroll
            for (int fq = 0; fq < 4; ++fq) {
                half4v hh = *(const half4v*)(pp + (fq * 16 + q16) * 4);
#pragma unroll
                for (int r = 0; r < 4; ++r)
                    a[fq * 4 + r] += wcc * (float)hh[r];
            }
        }
    }
    float id = 1.0f / den;
    float* op = out + (b * 2048 + qt * 128 + row) * 128 + g * 16;
#pragma unroll
    for (int uu = 0; uu < 4; ++uu) {
        float4 o;
        o.x = a[uu * 4]     * id;
        o.y = a[uu * 4 + 1] * id;
        o.z = a[uu * 4 + 2] * id;
        o.w = a[uu * 4 + 3] * id;
        *(float4*)(op + uu * 4) = o;
    }
}

extern "C" void kernel_launch(void* const* d_in, const int* in_sizes, int n_in,
                              void* d_out, int out_size, void* d_ws, size_t ws_size,
                              hipStream_t stream) {
    const float* x  = (const float*)d_in[0];
    const float* wq = (const float*)d_in[1];
    const float* wk = (const float*)d_in[2];
    const float* wv = (const float*)d_in[3];

    char* ws = (char*)d_ws;
    _Float16* wh   = (_Float16*)(ws);                    // 768 KB
    _Float16* qhp  = (_Float16*)(ws + (1u  << 20));      // 4 MB
    _Float16* khp  = (_Float16*)(ws + (5u  << 20));      // 4 MB
    _Float16* vtp  = (_Float16*)(ws + (9u  << 20));      // 4 MB
    _Float16* part = (_Float16*)(ws + (13u << 20));      // 576*32KB = 18 MB
    float*    stat = (float*)   (ws + (32u << 20));      // 590 KB

    wconv_k<<<192, 256, 0, stream>>>(wq, wk, wv, wh);
    qkv_k<<<768, 256, 0, stream>>>(x, wh, qhp, khp, vtp);
    attn_k<<<576, 512, 0, stream>>>(qhp, khp, vtp, part, stat, (float*)d_out);
    comb_k<<<448, 256, 0, stream>>>(part, stat, (float*)d_out);
}

// Round 21
// 72.175 us; speedup vs baseline: 1.3180x; 1.0938x over previous
//
#include <hip/hip_runtime.h>
#include <hip/hip_fp16.h>

typedef _Float16 half8  __attribute__((ext_vector_type(8)));
typedef _Float16 half4v __attribute__((ext_vector_type(4)));
typedef float    f32x4  __attribute__((ext_vector_type(4)));

#define MFMA_F16 __builtin_amdgcn_mfma_f32_16x16x32_f16

#define BAR_VM4() asm volatile("s_waitcnt vmcnt(4)\n\ts_barrier" ::: "memory")
#define BAR_VM0() asm volatile("s_waitcnt vmcnt(0)\n\ts_barrier" ::: "memory")

__device__ __forceinline__ unsigned pack_f16(float a, float b) {
    union { __fp16 h __attribute__((ext_vector_type(2))); unsigned u; } cv;
    cv.h = __builtin_amdgcn_cvt_pkrtz(a, b);
    return cv.u;
}

__device__ __forceinline__ void gload16(const void* g, void* l) {
    __builtin_amdgcn_global_load_lds((const __attribute__((address_space(1))) void*)g,
                                     (__attribute__((address_space(3))) void*)l, 16, 0, 0);
}

// ---------------- kernel 0: W_q|W_k|W_v f32 -> concat f16 [384][1024] ----------------
__global__ __launch_bounds__(256) void wconv_k(const float* __restrict__ wq,
                                               const float* __restrict__ wk,
                                               const float* __restrict__ wv,
                                               _Float16* __restrict__ wh) {
    int i = (blockIdx.x * 256 + threadIdx.x) * 8;
    const float* src; int off;
    if (i < 131072)      { src = wq; off = i; }
    else if (i < 262144) { src = wk; off = i - 131072; }
    else                 { src = wv; off = i - 262144; }
    float4 a = *(const float4*)(src + off);
    float4 b = *(const float4*)(src + off + 4);
    half8 h;
    h[0]=(_Float16)a.x; h[1]=(_Float16)a.y; h[2]=(_Float16)a.z; h[3]=(_Float16)a.w;
    h[4]=(_Float16)b.x; h[5]=(_Float16)b.y; h[6]=(_Float16)b.z; h[7]=(_Float16)b.w;
    *(half8*)(wh + i) = h;
}

// ---------------- kernel 1: fused QKV projection — clean T3/T4 pipeline ----------------
// grid 768, XCD-pinned: xcd = bid&7, slot = bid>>3; rb = (slot/3)*8 + xcd, cb = slot%3.
// Block: 64 rows x 128 cols. K-loop: 32 steps of K-32. BOTH x (f32) and W (f16) staged
// via global_load_lds into a 3-buffer rotation (48 KB); the ONLY VMEM in the loop are
// the 4 staging loads/tile -> exact counted vmcnt(4): the in-flight tile is never
// drained at the barrier. Swizzle on the pre-permuted global source (rule #21).
__global__ __launch_bounds__(256, 3) void qkv_k(const float* __restrict__ x,
                                                const _Float16* __restrict__ wh,
                                                _Float16* __restrict__ qh,
                                                _Float16* __restrict__ kh,
                                                _Float16* __restrict__ vth) {
    __shared__ float    xs[3][64 * 32];    // 8 KB each; rows 128B, src-swizzled (row&7)<<4
    __shared__ _Float16 wsb[3][128 * 32];  // 8 KB each; rows 64B,  src-swizzled (row&3)<<4
    const int tid = threadIdx.x;
    const int w = tid >> 6, l = tid & 63;
    const int fr = l & 15, fq = l >> 4;
    const int bid = blockIdx.x;
    const int xcd = bid & 7;
    const int slot = bid >> 3;
    const int rb = (slot / 3) * 8 + xcd;
    const int cb = slot % 3;
    const int row0 = rb * 64;
    const int c0 = cb * 128 + w * 32;
    const int xk = (fr & 7) << 4;          // x fragment-read XOR key

    // x staging lanes: issue i covers LDS bytes i*4096 + tid*16
    int xrow[2], xcol[2];                  // f32 index within row
#pragma unroll
    for (int i = 0; i < 2; ++i) {
        int ob = i * 4096 + tid * 16;
        xrow[i] = ob >> 7;
        xcol[i] = ((ob & 127) ^ ((xrow[i] & 7) << 4)) >> 2;
    }
    // W staging lanes
    int wrow_[2], wcol_[2];                // f16 index within row
#pragma unroll
    for (int i = 0; i < 2; ++i) {
        int ob = i * 4096 + tid * 16;
        wrow_[i] = ob >> 6;
        wcol_[i] = ((ob & 63) ^ ((wrow_[i] & 3) << 4)) >> 1;
    }

    f32x4 acc[4][2] = {};

#define STAGE(kt, bb) do {                                                                \
    _Pragma("unroll")                                                                     \
    for (int i = 0; i < 2; ++i)                                                           \
        gload16(x + (row0 + xrow[i]) * 1024 + (kt) * 32 + xcol[i],                        \
                (char*)(&xs[bb][0]) + i * 4096 + tid * 16);                               \
    _Pragma("unroll")                                                                     \
    for (int i = 0; i < 2; ++i)                                                           \
        gload16(wh + (cb * 128 + wrow_[i]) * 1024 + (kt) * 32 + wcol_[i],                 \
                (char*)(&wsb[bb][0]) + i * 4096 + tid * 16);                              \
    } while (0)

    // prologue: tiles 0,1 in flight
    STAGE(0, 0);
    STAGE(1, 1);

    int rd = 0, stg = 2;
    for (int kt = 0; kt < 32; ++kt) {
        if (kt < 31) BAR_VM4();            // oldest tile landed; newer stays in flight
        else         BAR_VM0();
        if (kt + 2 < 32) STAGE(kt + 2, stg);

        const char* xb = (const char*)(&xs[rd][0]);
        const char* wb = (const char*)(&wsb[rd][0]);
        half8 af[4];
#pragma unroll
        for (int mf = 0; mf < 4; ++mf) {
            const char* rp = xb + (mf * 16 + fr) * 128;
            float4 a0 = *(const float4*)(rp + ((fq * 32) ^ xk));
            float4 a1 = *(const float4*)(rp + ((fq * 32 + 16) ^ xk));
            union { unsigned u[4]; half8 h; } cv;
            cv.u[0] = pack_f16(a0.x, a0.y);
            cv.u[1] = pack_f16(a0.z, a0.w);
            cv.u[2] = pack_f16(a1.x, a1.y);
            cv.u[3] = pack_f16(a1.z, a1.w);
            af[mf] = cv.h;
        }
        half8 bf[2];
#pragma unroll
        for (int nf = 0; nf < 2; ++nf) {
            int wr = w * 32 + nf * 16 + fr;
            bf[nf] = *(const half8*)(wb + wr * 64 + ((fq * 16) ^ ((wr & 3) << 4)));
        }
        __builtin_amdgcn_s_setprio(1);
#pragma unroll
        for (int mf = 0; mf < 4; ++mf)
#pragma unroll
            for (int nf = 0; nf < 2; ++nf)
                acc[mf][nf] = MFMA_F16(af[mf], bf[nf], acc[mf][nf], 0, 0, 0);
        __builtin_amdgcn_s_setprio(0);

        stg = rd;
        rd = (rd == 2) ? 0 : rd + 1;
    }
#undef STAGE

    // epilogue: block-uniform destination (cb 0->Q, 1->K, 2->V-permuted)
#pragma unroll
    for (int nf = 0; nf < 2; ++nf) {
        int n0 = c0 + nf * 16 + fr;
#pragma unroll
        for (int mf = 0; mf < 4; ++mf) {
            int mb = row0 + mf * 16 + fq * 4;
            if (cb == 0) {
#pragma unroll
                for (int r = 0; r < 4; ++r) qh[(mb + r) * 128 + n0] = (_Float16)acc[mf][nf][r];
            } else if (cb == 1) {
#pragma unroll
                for (int r = 0; r < 4; ++r) kh[(mb + r) * 128 + (n0 - 128)] = (_Float16)acc[mf][nf][r];
            } else {
                half4v pv;
#pragma unroll
                for (int r = 0; r < 4; ++r) pv[r] = (_Float16)acc[mf][nf][r];
                int t = mb & 2047;
                int tl = t & 63;
                int tp = (t & ~63) | (tl & 35) | ((tl & 12) << 1) | ((tl & 16) >> 2);
                *(half4v*)(&vth[((mb >> 11) * 128 + (n0 - 256)) * 2048 + tp]) = pv;
            }
        }
    }
}

// ---------------- kernel 2: causal flash attention (unchanged from R20) ----------------
#define BAR_VMA() asm volatile("s_waitcnt vmcnt(0)\n\ts_barrier" ::: "memory")
__global__ __launch_bounds__(512, 4) void attn_k(const _Float16* __restrict__ qh,
                                                 const _Float16* __restrict__ kh,
                                                 const _Float16* __restrict__ vth,
                                                 _Float16* __restrict__ part,
                                                 float* __restrict__ stats,
                                                 float* __restrict__ out) {
    __shared__ _Float16 ks[2][32 * 128];
    __shared__ _Float16 vs[2][128 * 32];

    int bid = blockIdx.x;
    int b = bid & 7;
    int u = bid >> 3;
    int qt, c;
    {
        int idx = u;
        qt = 0;
        for (;;) { int nc = (qt >> 1) + 1; if (idx < nc) break; idx -= nc; ++qt; }
        c = idx;
    }
    int j0 = c * 8;
    int jmax = 4 * qt + 4;
    int j1 = j0 + 8 < jmax ? j0 + 8 : jmax;

    int tid = threadIdx.x, w = tid >> 6, l = tid & 63;
    int fr = l & 15, fq = l >> 4;
    int xw = (fr & 7) << 4;
    int xv = (fr & 3) << 4;

    const int kr  = tid >> 4;
    const int kc  = (tid & 15) ^ (kr & 7);
    const int vdd = tid >> 2;
    const int vc  = (tid & 3) ^ (vdd & 3);

    half8 qf[4];
    const _Float16* qp = qh + ((b * 2048 + qt * 128 + w * 16 + fr) << 7);
#pragma unroll
    for (int cc = 0; cc < 4; ++cc) qf[cc] = *(const half8*)(qp + cc * 32 + fq * 8);

#define GLOAD_TILE(j, bb) do {                                                            \
    gload16(kh + (((b << 11) + ((j) << 5) + kr) << 7) + kc * 8, &ks[bb][0] + w * 512);    \
    gload16(vth + (((b << 7) + vdd) << 11) + ((j) << 5) + vc * 8, &vs[bb][0] + w * 512);  \
    } while (0)

    f32x4 acc[8] = {};
    float mrow = -1e30f, lrow = 0.0f;

    GLOAD_TILE(j0, 0);
    BAR_VMA();
    if (j0 + 1 < j1) GLOAD_TILE(j0 + 1, 1);

    int cur = 0;
    for (int j = j0; j < j1; ++j) {
        const char* ksb = (const char*)(ks[cur]);
        const char* vsb = (const char*)(vs[cur]);

        f32x4 s[2] = {};
        __builtin_amdgcn_s_setprio(1);
#pragma unroll
        for (int n = 0; n < 2; ++n) {
            const char* krow = ksb + (n * 16 + fr) * 256;
#pragma unroll
            for (int cc = 0; cc < 4; ++cc) {
                half8 kf = *(const half8*)(krow + ((cc * 64 + fq * 16) ^ xw));
                s[n] = MFMA_F16(kf, qf[cc], s[n], 0, 0, 0);
            }
        }
        __builtin_amdgcn_s_setprio(0);
        const float sc = 0.088388347648318447f;  // 1/sqrt(128)
        if (j >= 4 * qt) {
            int koff = (j - 4 * qt) << 5;
            int qrow = w * 16 + fr;
#pragma unroll
            for (int n = 0; n < 2; ++n)
#pragma unroll
                for (int r = 0; r < 4; ++r) {
                    int kcol = koff + n * 16 + fq * 4 + r;
                    float v = s[n][r] * sc;
                    s[n][r] = (kcol > qrow) ? -1e30f : v;
                }
        } else {
#pragma unroll
            for (int n = 0; n < 2; ++n)
#pragma unroll
                for (int r = 0; r < 4; ++r) s[n][r] *= sc;
        }

        // online softmax with defer-max (T13)
        float pmax = s[0][0];
#pragma unroll
        for (int n = 0; n < 2; ++n)
#pragma unroll
            for (int r = 0; r < 4; ++r) pmax = fmaxf(pmax, s[n][r]);
        float al = 1.0f;
        if (!__all(pmax - mrow <= 8.0f)) {
            float mx = pmax;
            mx = fmaxf(mx, __shfl_xor(mx, 16));
            mx = fmaxf(mx, __shfl_xor(mx, 32));
            float nm = fmaxf(mrow, mx);
            al = __expf(mrow - nm);
            mrow = nm;
#pragma unroll
            for (int dt = 0; dt < 8; ++dt)
#pragma unroll
                for (int r = 0; r < 4; ++r) acc[dt][r] *= al;
        }
        float rs = 0.f;
#pragma unroll
        for (int n = 0; n < 2; ++n)
#pragma unroll
            for (int r = 0; r < 4; ++r) {
                float p = __expf(s[n][r] - mrow);
                s[n][r] = p;
                rs += p;
            }
        rs += __shfl_xor(rs, 16);
        rs += __shfl_xor(rs, 32);
        lrow = lrow * al + rs;

        union { unsigned u[4]; half8 h; } pb;
        pb.u[0] = pack_f16(s[0][0], s[0][1]);
        pb.u[1] = pack_f16(s[0][2], s[0][3]);
        pb.u[2] = pack_f16(s[1][0], s[1][1]);
        pb.u[3] = pack_f16(s[1][2], s[1][3]);

        __builtin_amdgcn_s_setprio(1);
#pragma unroll
        for (int dt = 0; dt < 8; ++dt) {
            const char* vrow = vsb + (dt * 16 + fr) * 64;
            half8 vf = *(const half8*)(vrow + ((fq * 16) ^ xv));
            acc[dt] = MFMA_F16(vf, pb.h, acc[dt], 0, 0, 0);
        }
        __builtin_amdgcn_s_setprio(0);

        BAR_VMA();
        if (j + 2 < j1) GLOAD_TILE(j + 2, cur);
        cur ^= 1;
    }

    float inv = 1.0f / lrow;

    if (qt < 2) {
        float* op = out + ((b * 2048 + qt * 128 + w * 16 + fr) << 7) + fq * 4;
#pragma unroll
        for (int dt = 0; dt < 8; ++dt) {
            float4 o;
            o.x = acc[dt][0] * inv; o.y = acc[dt][1] * inv;
            o.z = acc[dt][2] * inv; o.w = acc[dt][3] * inv;
            *(float4*)(op + dt * 16) = o;
        }
    } else {
        _Float16* op = part + bid * 16384 + w * 2048 + l * 4;
#pragma unroll
        for (int dt = 0; dt < 8; ++dt) {
            half4v h;
#pragma unroll
            for (int r = 0; r < 4; ++r) h[r] = (_Float16)(acc[dt][r] * inv);
            *(half4v*)(op + dt * 256) = h;
        }
        if (l < 16) {
            int ridx = bid * 128 + w * 16 + l;
            float2 st; st.x = mrow; st.y = lrow;
            *(float2*)(&stats[ridx * 2]) = st;
        }
    }
#undef GLOAD_TILE
}

// ---------------- kernel 3: combine split-KV partials (unchanged from R20) ----------------
__global__ __launch_bounds__(256) void comb_k(const _Float16* __restrict__ part,
                                              const float* __restrict__ stats,
                                              float* __restrict__ out) {
    int bid = blockIdx.x;
    int b = bid & 7;
    int rest = bid >> 3;
    int qt = 2 + (rest >> 2);
    int rh = rest & 3;
    int h = qt >> 1;
    int nc = h + 1;
    int u0 = qt + h * (h - 1) + (qt & 1) * h;
    int t = threadIdx.x;
    int row = rh * 32 + (t >> 3), g = t & 7;
    int w = row >> 4, q16 = row & 15;

    float mstar = -1e30f, mv[8], lv[8];
#pragma unroll
    for (int cc = 0; cc < 8; ++cc) {
        if (cc < nc) {
            int sidx = (((u0 + cc) << 3) + b) * 128 + row;
            mv[cc] = stats[sidx * 2];
            lv[cc] = stats[sidx * 2 + 1];
            mstar = fmaxf(mstar, mv[cc]);
        }
    }
    float den = 0.f, wc[8];
#pragma unroll
    for (int cc = 0; cc < 8; ++cc) {
        if (cc < nc) { wc[cc] = __expf(mv[cc] - mstar) * lv[cc]; den += wc[cc]; }
        else wc[cc] = 0.f;
    }
    float a[16] = {};
#pragma unroll
    for (int cc = 0; cc < 8; ++cc) {
        if (cc < nc) {
            const _Float16* pp = part + ((((u0 + cc) << 3) + b) * 16384) + w * 2048 + g * 256;
            float wcc = wc[cc];
#pragma unroll
            for (int fq = 0; fq < 4; ++fq) {
                half4v hh = *(const half4v*)(pp + (fq * 16 + q16) * 4);
#pragma unroll
                for (int r = 0; r < 4; ++r)
                    a[fq * 4 + r] += wcc * (float)hh[r];
            }
        }
    }
    float id = 1.0f / den;
    float* op = out + (b * 2048 + qt * 128 + row) * 128 + g * 16;
#pragma unroll
    for (int uu = 0; uu < 4; ++uu) {
        float4 o;
        o.x = a[uu * 4]     * id;
        o.y = a[uu * 4 + 1] * id;
        o.z = a[uu * 4 + 2] * id;
        o.w = a[uu * 4 + 3] * id;
        *(float4*)(op + uu * 4) = o;
    }
}

extern "C" void kernel_launch(void* const* d_in, const int* in_sizes, int n_in,
                              void* d_out, int out_size, void* d_ws, size_t ws_size,
                              hipStream_t stream) {
    const float* x  = (const float*)d_in[0];
    const float* wq = (const float*)d_in[1];
    const float* wk = (const float*)d_in[2];
    const float* wv = (const float*)d_in[3];

    char* ws = (char*)d_ws;
    _Float16* wh   = (_Float16*)(ws);                    // 768 KB
    _Float16* qhp  = (_Float16*)(ws + (1u  << 20));      // 4 MB
    _Float16* khp  = (_Float16*)(ws + (5u  << 20));      // 4 MB
    _Float16* vtp  = (_Float16*)(ws + (9u  << 20));      // 4 MB
    _Float16* part = (_Float16*)(ws + (13u << 20));      // 576*32KB = 18 MB
    float*    stat = (float*)   (ws + (32u << 20));      // 590 KB

    wconv_k<<<192, 256, 0, stream>>>(wq, wk, wv, wh);
    qkv_k<<<768, 256, 0, stream>>>(x, wh, qhp, khp, vtp);
    attn_k<<<576, 512, 0, stream>>>(qhp, khp, vtp, part, stat, (float*)d_out);
    comb_k<<<448, 256, 0, stream>>>(part, stat, (float*)d_out);
}